// Round 4
// baseline (73.788 us; speedup 1.0000x reference)
//
#include <hip/hip_runtime.h>
#include <hip/hip_bf16.h>

#define IN_DIM 512
#define OUT_DIM 512
#define BATCH 4096
#define NC 9                  // 8 active spline basis slots + 1 silu slot
#define KDIM (IN_DIM * NC)    // 4608
#define NCTRL 17
#define TM 128                // batch rows per block
#define TN 128                // out cols per block
#define BK 64
#define SPLITK 2
#define KSLICE (KDIM / SPLITK)   // 2304
#define NT (KSLICE / BK)         // 36 K-steps per block
// ring buffer: 4 x (TM*BK + TN*BK) bf16 = 4 x 32768 B = 128 KiB LDS (dynamic)
#define BUF_ELEMS ((TM + TN) * BK)   // 16384
#define BUF_BYTES (BUF_ELEMS * 2)    // 32768

typedef unsigned short ushort_t;
typedef __attribute__((ext_vector_type(8))) short short8;
typedef __attribute__((ext_vector_type(4))) float f32x4;

__device__ inline ushort_t to_bf16(float f) {
    union { float f; unsigned int i; } v; v.f = f;
    unsigned int r = v.i + 0x7FFF + ((v.i >> 16) & 1);   // round-to-nearest-even
    return (ushort_t)(r >> 16);
}

__device__ inline void gld16(const ushort_t* g, void* l) {
    __builtin_amdgcn_global_load_lds(
        (const __attribute__((address_space(1))) void*)g,
        (__attribute__((address_space(3))) void*)l, 16, 0, 0);
}

// Pre-swizzled storage: element (row R, col k) lives at col k ^ ((R&7)<<3).
// XOR permutes 16B chunks inside each 128B segment, so linear global_load_lds
// staging of 64-col tiles is unaffected; ds_read applies the same XOR ->
// conflict-free b128 phases (verified: SQ_LDS_BANK_CONFLICT == 0).

// Fused prep: blocks [0,BATCH) build B' rows, blocks [BATCH,BATCH+OUT_DIM) build A' rows.
// B'[b][i*9+c] = basis_c(t) (c<8), silu(t) (c==8);  A'[o][i*9+c] = w_s*ctrl (c<8), w_b (c==8).
// Both stage the swizzled row in LDS then store coalesced 16B chunks.
__global__ __launch_bounds__(512) void prep_AB(const float* __restrict__ x,
                                               const float* __restrict__ g,
                                               const float* __restrict__ bound_p,
                                               const float* __restrict__ w_b,
                                               const float* __restrict__ w_s,
                                               const float* __restrict__ ctrl,
                                               ushort_t* __restrict__ Bt,
                                               ushort_t* __restrict__ A) {
    __shared__ ushort_t rowbuf[KDIM];
    int blk = blockIdx.x;
    int i = threadIdx.x;
    ushort_t* dstrow;
    if (blk < BATCH) {
        int b = blk;
        float bound = bound_p[0];
        float t = x[(size_t)b * IN_DIM + i];
        t = fminf(fmaxf(t, -bound), bound);
        float u = (t + 8.0f) * 0.625f;       // knot spacing 1.6
        int j = (int)u;                       // g[j] <= t < g[j+1], j in [2,7]
        j = min(max(j, 2), 7);
        float gj[6];
#pragma unroll
        for (int r = 0; r < 6; r++) gj[r] = g[j - 2 + r];
        // de Boor; uniform knots -> denominators are p*1.6 (constants)
        const float invph[4] = {0.f, 0.625f, 0.3125f, 0.2083333333f};
        float Nv[4]; Nv[0] = 1.0f;
        float lv[4], rv[4];
#pragma unroll
        for (int p = 1; p <= 3; p++) {
            lv[p] = t - gj[3 - p];
            rv[p] = gj[2 + p] - t;
            float saved = 0.0f;
#pragma unroll
            for (int r = 0; r < p; r++) {
                float temp = Nv[r] * invph[p];
                Nv[r] = saved + rv[r + 1] * temp;
                saved = lv[p - r] * temp;
            }
            Nv[p] = saved;
        }
        int c0 = j - 3;                       // c0==-1 at j==2: Nv[0] (B_{-1}) dropped
        int swz = (b & 7) << 3;
        int k0 = i * NC;
#pragma unroll
        for (int c = 0; c < 8; c++) {
            float v = 0.0f;
            v = (c == c0    ) ? Nv[0] : v;
            v = (c == c0 + 1) ? Nv[1] : v;
            v = (c == c0 + 2) ? Nv[2] : v;
            v = (c == c0 + 3) ? Nv[3] : v;
            rowbuf[(k0 + c) ^ swz] = to_bf16(v);
        }
        float sg = 1.0f / (1.0f + __expf(-t));
        rowbuf[(k0 + 8) ^ swz] = to_bf16(t * sg);
        dstrow = Bt + (size_t)b * KDIM;
    } else {
        int o = blk - BATCH;
        float ws = w_s[(size_t)i * OUT_DIM + o];
        float wb = w_b[(size_t)i * OUT_DIM + o];
        const float* cp = ctrl + ((size_t)i * OUT_DIM + o) * NCTRL;
        int swz = (o & 7) << 3;
        int k0 = i * NC;
#pragma unroll
        for (int c = 0; c < 8; c++) rowbuf[(k0 + c) ^ swz] = to_bf16(ws * cp[c]);
        rowbuf[(k0 + 8) ^ swz] = to_bf16(wb);
        dstrow = A + (size_t)o * KDIM;
    }
    __syncthreads();
    const uint4* s = (const uint4*)rowbuf;               // 576 x 16B chunks
    uint4* d = (uint4*)dstrow;
    d[i] = s[i];
    if (i < 64) d[512 + i] = s[512 + i];
}

// C[b][o] = sum_k B'[b][k] * A'[o][k].  TM=TN=128, 4 waves (2x2 of 64x64,
// 4x4 acc), BK=64, ring-4 LDS (128KB dynamic), counted vmcnt (never 0 in
// main loop), one s_barrier per K-step. Split-K=2 via fp32 atomicAdd.
__global__ __launch_bounds__(256) void gemm_kan(const ushort_t* __restrict__ A,
                                                const ushort_t* __restrict__ Bt,
                                                float* __restrict__ out) {
    extern __shared__ ushort_t ring[];   // 4 * BUF_ELEMS = 128 KiB
    int tid = threadIdx.x;
    int lane = tid & 63;
    int w = tid >> 6;             // 0..3
    int bid = blockIdx.x;
    // bid = ot*64 + kz*32 + bt: the 4 ot-blocks sharing a (bt,kz) B'-panel
    // differ by 64 -> equal bid mod 8 -> same XCD -> panel L2-shared.
    int ot = bid >> 6;            // 0..3
    int kz = (bid >> 5) & 1;      // 0..1
    int bt = bid & 31;            // 0..31
    int brow0 = bt * TM;
    int ocol0 = ot * TN;
    int k0 = kz * KSLICE;

    int wr = w >> 1;              // 0..1 : M sub-tile (64 rows)
    int wc = w & 1;               // 0..1 : N sub-tile (64 cols)

    f32x4 acc[4][4];
#pragma unroll
    for (int m = 0; m < 4; m++)
#pragma unroll
        for (int n = 0; n < 4; n++) acc[m][n] = (f32x4){0.f, 0.f, 0.f, 0.f};

    // staging: 32 x 1KB issues/step (16 for Xs=B'-tile, 16 for Ys=A'-tile);
    // wave w owns issues f = 8w..8w+7. LDS dst linear: f*1024.
    int lr = lane >> 3;           // row within 8-row group
    int lcb = (lane & 7) * 8;     // 16B chunk within 64-col row
    const ushort_t* src[8];
    int ldsoff[8];
#pragma unroll
    for (int i = 0; i < 8; i++) {
        int f = w * 8 + i;
        const ushort_t* basep = (f < 16)
            ? Bt + (size_t)(brow0 + f * 8 + lr) * KDIM
            : A  + (size_t)(ocol0 + (f - 16) * 8 + lr) * KDIM;
        src[i] = basep + k0 + lcb;
        ldsoff[i] = f * 1024;
    }
    char* ringb = (char*)ring;

#define STAGE(T) do { int bb_ = ((T) & 3) * BUF_BYTES;                         \
    _Pragma("unroll") for (int i_ = 0; i_ < 8; i_++)                           \
        gld16(src[i_] + (size_t)(T) * BK, ringb + bb_ + ldsoff[i_]); } while (0)

#define COMPUTE(T) do {                                                        \
    const ushort_t* Xs_ = ring + ((T) & 3) * BUF_ELEMS;                        \
    const ushort_t* Ys_ = Xs_ + TM * BK;                                       \
    int xrow_ = wr * 64 + (lane & 15);                                         \
    int yrow_ = wc * 64 + (lane & 15);                                         \
    int swz_ = (lane & 7) << 3;                                                \
    _Pragma("unroll") for (int kk_ = 0; kk_ < 2; kk_++) {                      \
        int kofs_ = (kk_ * 32 + ((lane >> 4) << 3)) ^ swz_;                    \
        short8 xf[4], yf[4];                                                   \
        _Pragma("unroll") for (int m_ = 0; m_ < 4; m_++)                       \
            xf[m_] = *(const short8*)&Xs_[(xrow_ + m_ * 16) * BK + kofs_];     \
        _Pragma("unroll") for (int n_ = 0; n_ < 4; n_++)                       \
            yf[n_] = *(const short8*)&Ys_[(yrow_ + n_ * 16) * BK + kofs_];     \
        _Pragma("unroll") for (int m_ = 0; m_ < 4; m_++)                       \
            _Pragma("unroll") for (int n_ = 0; n_ < 4; n_++)                   \
                acc[m_][n_] = __builtin_amdgcn_mfma_f32_16x16x32_bf16(         \
                    xf[m_], yf[n_], acc[m_][n_], 0, 0, 0);                     \
    } } while (0)

#define WAITVM(N) asm volatile("s_waitcnt vmcnt(" #N ")" ::: "memory")
#define BARRIER() do { __builtin_amdgcn_sched_barrier(0);                      \
    __builtin_amdgcn_s_barrier();                                              \
    __builtin_amdgcn_sched_barrier(0); } while (0)

    // prologue: 3 tiles in flight (24 gld16/wave outstanding)
    STAGE(0); STAGE(1); STAGE(2);
    // steady state: wait tile t (leave 16 = 2 tiles in flight), barrier,
    // stage t+3 (into buffer freed by compute t-1, safe past this barrier),
    // compute t.
    for (int t = 0; t < NT - 3; ++t) {
        WAITVM(16);
        BARRIER();
        STAGE(t + 3);
        COMPUTE(t);
    }
    WAITVM(16); BARRIER(); COMPUTE(NT - 3);
    WAITVM(8);  BARRIER(); COMPUTE(NT - 2);
    WAITVM(0);  BARRIER(); COMPUTE(NT - 1);

    // epilogue: C/D layout col=lane&15, row=(lane>>4)*4+reg (m89)
    int rgrp = (lane >> 4) * 4;
    int cidx = lane & 15;
#pragma unroll
    for (int m = 0; m < 4; m++) {
#pragma unroll
        for (int n = 0; n < 4; n++) {
            int o_idx = ocol0 + wc * 64 + n * 16 + cidx;
            int b_base = brow0 + wr * 64 + m * 16 + rgrp;
#pragma unroll
            for (int r = 0; r < 4; r++)
                atomicAdd(out + (size_t)(b_base + r) * OUT_DIM + o_idx, acc[m][n][r]);
        }
    }
#undef STAGE
#undef COMPUTE
#undef WAITVM
#undef BARRIER
}

extern "C" void kernel_launch(void* const* d_in, const int* in_sizes, int n_in,
                              void* d_out, int out_size, void* d_ws, size_t ws_size,
                              hipStream_t stream) {
    const float* x     = (const float*)d_in[0];
    const float* w_b   = (const float*)d_in[1];
    const float* w_s   = (const float*)d_in[2];
    const float* ctrl  = (const float*)d_in[3];
    const float* g     = (const float*)d_in[4];
    const float* bound = (const float*)d_in[5];
    float* out = (float*)d_out;

    ushort_t* Abuf = (ushort_t*)d_ws;                               // 512*4608*2 = 4.72 MB
    ushort_t* Bbuf = (ushort_t*)((char*)d_ws + (size_t)(8u << 20)); // at 8 MB; 4096*4608*2 = 37.75 MB

    static int lds_ok = 0;
    if (!lds_ok) {   // idempotent host-side attribute set (not a stream op)
        hipFuncSetAttribute((const void*)gemm_kan,
                            hipFuncAttributeMaxDynamicSharedMemorySize,
                            4 * BUF_BYTES);
        lds_ok = 1;
    }

    hipMemsetAsync(d_out, 0, (size_t)BATCH * OUT_DIM * sizeof(float), stream);
    prep_AB<<<BATCH + OUT_DIM, 512, 0, stream>>>(x, g, bound, w_b, w_s, ctrl, Bbuf, Abuf);
    gemm_kan<<<(BATCH / TM) * (OUT_DIM / TN) * SPLITK, 256, 4 * BUF_BYTES, stream>>>(Abuf, Bbuf, out);
}

// Round 5
// 73.243 us; speedup vs baseline: 1.0074x; 1.0074x over previous
//
#include <hip/hip_runtime.h>
#include <hip/hip_bf16.h>

#define IN_DIM 512
#define OUT_DIM 512
#define BATCH 4096
#define NC 9                  // 8 active spline basis slots + 1 silu slot
#define KDIM (IN_DIM * NC)    // 4608
#define NCTRL 17
#define TM 256                // batch rows per block
#define TN 128                // out cols per block
#define BK 64
#define SPLITK 4
#define KSLICE (KDIM / SPLITK)   // 1152
#define NT (KSLICE / BK)         // 18 K-steps per block
// ring buffer: 3 x (TM*BK + TN*BK) bf16 = 3 x 49152 B = 144 KiB LDS (dynamic)
#define BUF_ELEMS ((TM + TN) * BK)   // 24576
#define BUF_BYTES (BUF_ELEMS * 2)    // 49152

typedef unsigned short ushort_t;
typedef __attribute__((ext_vector_type(8))) short short8;
typedef __attribute__((ext_vector_type(4))) float f32x4;

__device__ inline ushort_t to_bf16(float f) {
    union { float f; unsigned int i; } v; v.f = f;
    unsigned int r = v.i + 0x7FFF + ((v.i >> 16) & 1);   // round-to-nearest-even
    return (ushort_t)(r >> 16);
}

__device__ inline void gld16(const ushort_t* g, void* l) {
    __builtin_amdgcn_global_load_lds(
        (const __attribute__((address_space(1))) void*)g,
        (__attribute__((address_space(3))) void*)l, 16, 0, 0);
}

// Pre-swizzled storage: element (row R, col k) lives at col k ^ ((R&7)<<3).
// XOR permutes 16B chunks inside each 128B segment: linear global_load_lds
// staging of 64-col tiles is unaffected; ds_read applies the same XOR.
// Verified conflict-free (SQ_LDS_BANK_CONFLICT == 0 in R2/R4).

// Fused prep: blocks [0,BATCH) build B' rows (and zero their d_out row),
// blocks [BATCH,BATCH+OUT_DIM) build A' rows.
__global__ __launch_bounds__(512) void prep_AB(const float* __restrict__ x,
                                               const float* __restrict__ g,
                                               const float* __restrict__ bound_p,
                                               const float* __restrict__ w_b,
                                               const float* __restrict__ w_s,
                                               const float* __restrict__ ctrl,
                                               ushort_t* __restrict__ Bt,
                                               ushort_t* __restrict__ A,
                                               float* __restrict__ out) {
    __shared__ ushort_t rowbuf[KDIM];
    int blk = blockIdx.x;
    int i = threadIdx.x;
    ushort_t* dstrow;
    if (blk < BATCH) {
        int b = blk;
        out[(size_t)b * OUT_DIM + i] = 0.0f;   // zero d_out row for atomic epilogue
        float bound = bound_p[0];
        float t = x[(size_t)b * IN_DIM + i];
        t = fminf(fmaxf(t, -bound), bound);
        float u = (t + 8.0f) * 0.625f;       // knot spacing 1.6
        int j = (int)u;                       // g[j] <= t < g[j+1], j in [2,7]
        j = min(max(j, 2), 7);
        float gj[6];
#pragma unroll
        for (int r = 0; r < 6; r++) gj[r] = g[j - 2 + r];
        // de Boor; uniform knots -> denominators are p*1.6 (constants)
        const float invph[4] = {0.f, 0.625f, 0.3125f, 0.2083333333f};
        float Nv[4]; Nv[0] = 1.0f;
        float lv[4], rv[4];
#pragma unroll
        for (int p = 1; p <= 3; p++) {
            lv[p] = t - gj[3 - p];
            rv[p] = gj[2 + p] - t;
            float saved = 0.0f;
#pragma unroll
            for (int r = 0; r < p; r++) {
                float temp = Nv[r] * invph[p];
                Nv[r] = saved + rv[r + 1] * temp;
                saved = lv[p - r] * temp;
            }
            Nv[p] = saved;
        }
        int c0 = j - 3;                       // c0==-1 at j==2: Nv[0] (B_{-1}) dropped
        int swz = (b & 7) << 3;
        int k0 = i * NC;
#pragma unroll
        for (int c = 0; c < 8; c++) {
            float v = 0.0f;
            v = (c == c0    ) ? Nv[0] : v;
            v = (c == c0 + 1) ? Nv[1] : v;
            v = (c == c0 + 2) ? Nv[2] : v;
            v = (c == c0 + 3) ? Nv[3] : v;
            rowbuf[(k0 + c) ^ swz] = to_bf16(v);
        }
        float sg = 1.0f / (1.0f + __expf(-t));
        rowbuf[(k0 + 8) ^ swz] = to_bf16(t * sg);
        dstrow = Bt + (size_t)b * KDIM;
    } else {
        int o = blk - BATCH;
        float ws = w_s[(size_t)i * OUT_DIM + o];
        float wb = w_b[(size_t)i * OUT_DIM + o];
        const float* cp = ctrl + ((size_t)i * OUT_DIM + o) * NCTRL;
        int swz = (o & 7) << 3;
        int k0 = i * NC;
#pragma unroll
        for (int c = 0; c < 8; c++) rowbuf[(k0 + c) ^ swz] = to_bf16(ws * cp[c]);
        rowbuf[(k0 + 8) ^ swz] = to_bf16(wb);
        dstrow = A + (size_t)o * KDIM;
    }
    __syncthreads();
    const uint4* s = (const uint4*)rowbuf;               // 576 x 16B chunks
    uint4* d = (uint4*)dstrow;
    d[i] = s[i];
    if (i < 64) d[512 + i] = s[512 + i];
}

// C[b][o] = sum_k B'[b][k] * A'[o][k].  TM=256 x TN=128, 4 waves (2x2 of
// 128x64 each, acc 8x4), BK=64, ring-3 LDS (144 KB), counted vmcnt (never 0
// in main loop), one s_barrier per K-step. Split-K=4 via fp32 atomicAdd.
__global__ __launch_bounds__(256, 1) void gemm_kan(const ushort_t* __restrict__ A,
                                                   const ushort_t* __restrict__ Bt,
                                                   float* __restrict__ out) {
    extern __shared__ ushort_t ring[];   // 3 * BUF_ELEMS = 144 KiB
    int tid = threadIdx.x;
    int lane = tid & 63;
    int w = tid >> 6;             // 0..3
    int bid = blockIdx.x;
    // bid = ot*64 + kz*16 + bt: the 4 ot-blocks sharing a (bt,kz) B'-slab
    // differ by 64 -> equal bid mod 8 -> same XCD -> slab L2-shared.
    int ot = bid >> 6;            // 0..3
    int kz = (bid >> 4) & 3;      // 0..3
    int bt = bid & 15;            // 0..15
    int brow0 = bt * TM;
    int ocol0 = ot * TN;
    int k0 = kz * KSLICE;

    int wr = w >> 1;              // 0..1 : M sub-tile (128 rows of 256)
    int wc = w & 1;               // 0..1 : N sub-tile (64 cols of 128)

    f32x4 acc[8][4];
#pragma unroll
    for (int m = 0; m < 8; m++)
#pragma unroll
        for (int n = 0; n < 4; n++) acc[m][n] = (f32x4){0.f, 0.f, 0.f, 0.f};

    // staging: 48 x 1KB issues/step (32 for Xs=B'-tile 256 rows, 16 for
    // Ys=A'-tile 128 rows); wave w owns f = 12w..12w+11. LDS dst = f*1024.
    int lr = lane >> 3;           // row within 8-row group
    int lcb = (lane & 7) * 8;     // 16B chunk within 64-col row
    const ushort_t* src[12];
    int ldsoff[12];
#pragma unroll
    for (int i = 0; i < 12; i++) {
        int f = w * 12 + i;
        const ushort_t* basep = (f < 32)
            ? Bt + (size_t)(brow0 + f * 8 + lr) * KDIM
            : A  + (size_t)(ocol0 + (f - 32) * 8 + lr) * KDIM;
        src[i] = basep + k0 + lcb;
        ldsoff[i] = f * 1024;
    }
    char* ringb = (char*)ring;

// stages the NEXT tile (pointers auto-advance); each tile = 12 issues/wave
#define STAGE(B) do { char* bb_ = ringb + (B) * BUF_BYTES;                     \
    _Pragma("unroll") for (int i_ = 0; i_ < 12; i_++) {                        \
        gld16(src[i_], bb_ + ldsoff[i_]); src[i_] += BK; } } while (0)

#define COMPUTE(B) do {                                                        \
    const ushort_t* Xs_ = ring + (B) * BUF_ELEMS;                              \
    const ushort_t* Ys_ = Xs_ + TM * BK;                                       \
    int xrow_ = wr * 128 + (lane & 15);                                        \
    int yrow_ = wc * 64 + (lane & 15);                                         \
    int swz_ = (lane & 7) << 3;                                                \
    _Pragma("unroll") for (int kk_ = 0; kk_ < 2; kk_++) {                      \
        int kofs_ = (kk_ * 32 + ((lane >> 4) << 3)) ^ swz_;                    \
        short8 xf[8], yf[4];                                                   \
        _Pragma("unroll") for (int m_ = 0; m_ < 8; m_++)                       \
            xf[m_] = *(const short8*)&Xs_[(xrow_ + m_ * 16) * BK + kofs_];     \
        _Pragma("unroll") for (int n_ = 0; n_ < 4; n_++)                       \
            yf[n_] = *(const short8*)&Ys_[(yrow_ + n_ * 16) * BK + kofs_];     \
        _Pragma("unroll") for (int m_ = 0; m_ < 8; m_++)                       \
            _Pragma("unroll") for (int n_ = 0; n_ < 4; n_++)                   \
                acc[m_][n_] = __builtin_amdgcn_mfma_f32_16x16x32_bf16(         \
                    xf[m_], yf[n_], acc[m_][n_], 0, 0, 0);                     \
    } } while (0)

#define WAITVM(N) asm volatile("s_waitcnt vmcnt(" #N ")" ::: "memory")
#define BARRIER() do { __builtin_amdgcn_sched_barrier(0);                      \
    __builtin_amdgcn_s_barrier();                                              \
    __builtin_amdgcn_sched_barrier(0); } while (0)

    // prologue: 2 tiles in flight (24 gld16/wave outstanding)
    STAGE(0); STAGE(1);
    // steady: wait tile t (leave 12 = next tile in flight), barrier,
    // stage t+2 into the buffer freed by compute(t-1), compute t.
    int cbuf = 0, sbuf = 2;
    for (int t = 0; t < NT - 2; ++t) {
        WAITVM(12);
        BARRIER();
        STAGE(sbuf);
        COMPUTE(cbuf);
        cbuf = (cbuf == 2) ? 0 : cbuf + 1;
        sbuf = (sbuf == 2) ? 0 : sbuf + 1;
    }
    WAITVM(12); BARRIER(); COMPUTE(cbuf);
    cbuf = (cbuf == 2) ? 0 : cbuf + 1;
    WAITVM(0);  BARRIER(); COMPUTE(cbuf);

    // epilogue: C/D layout col=lane&15, row=(lane>>4)*4+reg (m89)
    int rgrp = (lane >> 4) * 4;
    int cidx = lane & 15;
#pragma unroll
    for (int m = 0; m < 8; m++) {
#pragma unroll
        for (int n = 0; n < 4; n++) {
            int o_idx = ocol0 + wc * 64 + n * 16 + cidx;
            int b_base = brow0 + wr * 128 + m * 16 + rgrp;
#pragma unroll
            for (int r = 0; r < 4; r++)
                atomicAdd(out + (size_t)(b_base + r) * OUT_DIM + o_idx, acc[m][n][r]);
        }
    }
#undef STAGE
#undef COMPUTE
#undef WAITVM
#undef BARRIER
}

extern "C" void kernel_launch(void* const* d_in, const int* in_sizes, int n_in,
                              void* d_out, int out_size, void* d_ws, size_t ws_size,
                              hipStream_t stream) {
    const float* x     = (const float*)d_in[0];
    const float* w_b   = (const float*)d_in[1];
    const float* w_s   = (const float*)d_in[2];
    const float* ctrl  = (const float*)d_in[3];
    const float* g     = (const float*)d_in[4];
    const float* bound = (const float*)d_in[5];
    float* out = (float*)d_out;

    ushort_t* Abuf = (ushort_t*)d_ws;                               // 512*4608*2 = 4.72 MB
    ushort_t* Bbuf = (ushort_t*)((char*)d_ws + (size_t)(8u << 20)); // at 8 MB; 4096*4608*2 = 37.75 MB

    static int lds_ok = 0;
    if (!lds_ok) {   // idempotent host-side attribute set (not a stream op)
        hipFuncSetAttribute((const void*)gemm_kan,
                            hipFuncAttributeMaxDynamicSharedMemorySize,
                            3 * BUF_BYTES);
        lds_ok = 1;
    }

    prep_AB<<<BATCH + OUT_DIM, 512, 0, stream>>>(x, g, bound, w_b, w_s, ctrl,
                                                 Bbuf, Abuf, out);
    gemm_kan<<<(BATCH / TM) * (OUT_DIM / TN) * SPLITK, 256, 3 * BUF_BYTES, stream>>>(Abuf, Bbuf, out);
}

// Round 6
// 67.545 us; speedup vs baseline: 1.0924x; 1.0844x over previous
//
#include <hip/hip_runtime.h>
#include <hip/hip_bf16.h>

#define IN_DIM 512
#define OUT_DIM 512
#define BATCH 4096
#define NC 9                  // 8 active spline basis slots + 1 silu slot
#define KDIM (IN_DIM * NC)    // 4608
#define NCTRL 17
#define TM 128                // batch rows per block
#define TN 128                // out cols per block
#define BK 64
#define SPLITK 4
#define KSLICE (KDIM / SPLITK)   // 1152
#define NT (KSLICE / BK)         // 18 K-steps per block
// ring-2: 2 x (TM+TN)*BK bf16 = 2 x 32768 B = 64 KiB LDS -> 2 blocks/CU
#define BUF_ELEMS ((TM + TN) * BK)   // 16384
#define BUF_BYTES (BUF_ELEMS * 2)    // 32768

typedef unsigned short ushort_t;
typedef __attribute__((ext_vector_type(8))) short short8;
typedef __attribute__((ext_vector_type(4))) float f32x4;

__device__ inline ushort_t to_bf16(float f) {
    union { float f; unsigned int i; } v; v.f = f;
    unsigned int r = v.i + 0x7FFF + ((v.i >> 16) & 1);   // round-to-nearest-even
    return (ushort_t)(r >> 16);
}

__device__ inline void gld16(const ushort_t* g, void* l) {
    __builtin_amdgcn_global_load_lds(
        (const __attribute__((address_space(1))) void*)g,
        (__attribute__((address_space(3))) void*)l, 16, 0, 0);
}

// Pre-swizzled storage: element (row R, col k) lives at col k ^ ((R&7)<<3).
// XOR permutes 16B chunks inside each 128B segment: linear global_load_lds
// staging of 64-col tiles is unaffected; ds_read applies the same XOR.
// Verified conflict-free (SQ_LDS_BANK_CONFLICT == 0 in R2/R4/R5).

// Fused prep: blocks [0,BATCH) build B' rows (and zero their d_out row),
// blocks [BATCH,BATCH+OUT_DIM) build A' rows.
__global__ __launch_bounds__(512) void prep_AB(const float* __restrict__ x,
                                               const float* __restrict__ g,
                                               const float* __restrict__ bound_p,
                                               const float* __restrict__ w_b,
                                               const float* __restrict__ w_s,
                                               const float* __restrict__ ctrl,
                                               ushort_t* __restrict__ Bt,
                                               ushort_t* __restrict__ A,
                                               float* __restrict__ out) {
    __shared__ ushort_t rowbuf[KDIM];
    int blk = blockIdx.x;
    int i = threadIdx.x;
    ushort_t* dstrow;
    if (blk < BATCH) {
        int b = blk;
        out[(size_t)b * OUT_DIM + i] = 0.0f;   // zero d_out row for atomic epilogue
        float bound = bound_p[0];
        float t = x[(size_t)b * IN_DIM + i];
        t = fminf(fmaxf(t, -bound), bound);
        float u = (t + 8.0f) * 0.625f;       // knot spacing 1.6
        int j = (int)u;                       // g[j] <= t < g[j+1], j in [2,7]
        j = min(max(j, 2), 7);
        float gj[6];
#pragma unroll
        for (int r = 0; r < 6; r++) gj[r] = g[j - 2 + r];
        // de Boor; uniform knots -> denominators are p*1.6 (constants)
        const float invph[4] = {0.f, 0.625f, 0.3125f, 0.2083333333f};
        float Nv[4]; Nv[0] = 1.0f;
        float lv[4], rv[4];
#pragma unroll
        for (int p = 1; p <= 3; p++) {
            lv[p] = t - gj[3 - p];
            rv[p] = gj[2 + p] - t;
            float saved = 0.0f;
#pragma unroll
            for (int r = 0; r < p; r++) {
                float temp = Nv[r] * invph[p];
                Nv[r] = saved + rv[r + 1] * temp;
                saved = lv[p - r] * temp;
            }
            Nv[p] = saved;
        }
        int c0 = j - 3;                       // c0==-1 at j==2: Nv[0] (B_{-1}) dropped
        int swz = (b & 7) << 3;
        int k0 = i * NC;
#pragma unroll
        for (int c = 0; c < 8; c++) {
            float v = 0.0f;
            v = (c == c0    ) ? Nv[0] : v;
            v = (c == c0 + 1) ? Nv[1] : v;
            v = (c == c0 + 2) ? Nv[2] : v;
            v = (c == c0 + 3) ? Nv[3] : v;
            rowbuf[(k0 + c) ^ swz] = to_bf16(v);
        }
        float sg = 1.0f / (1.0f + __expf(-t));
        rowbuf[(k0 + 8) ^ swz] = to_bf16(t * sg);
        dstrow = Bt + (size_t)b * KDIM;
    } else {
        int o = blk - BATCH;
        float ws = w_s[(size_t)i * OUT_DIM + o];
        float wb = w_b[(size_t)i * OUT_DIM + o];
        const float* cp = ctrl + ((size_t)i * OUT_DIM + o) * NCTRL;
        int swz = (o & 7) << 3;
        int k0 = i * NC;
#pragma unroll
        for (int c = 0; c < 8; c++) rowbuf[(k0 + c) ^ swz] = to_bf16(ws * cp[c]);
        rowbuf[(k0 + 8) ^ swz] = to_bf16(wb);
        dstrow = A + (size_t)o * KDIM;
    }
    __syncthreads();
    const uint4* s = (const uint4*)rowbuf;               // 576 x 16B chunks
    uint4* d = (uint4*)dstrow;
    d[i] = s[i];
    if (i < 64) d[512 + i] = s[512 + i];
}

// C[b][o] = sum_k B'[b][k] * A'[o][k].  TM=TN=128, 8 waves (4x2 of 32x64,
// acc 2x4), BK=64, ring-2 LDS (64 KB -> 2 blocks/CU -> 4 waves/SIMD),
// counted vmcnt (never 0 in main loop), 2 barriers/step. Split-K=4 via
// fp32 atomicAdd into out zeroed by prep_AB.
__global__ __launch_bounds__(512, 4) void gemm_kan(const ushort_t* __restrict__ A,
                                                   const ushort_t* __restrict__ Bt,
                                                   float* __restrict__ out) {
    __shared__ ushort_t ring[2 * BUF_ELEMS];   // 64 KiB
    int tid = threadIdx.x;
    int lane = tid & 63;
    int w = tid >> 6;             // 0..7
    int bid = blockIdx.x;
    // bid = ot*128 + kz*32 + bt: the 4 ot-blocks sharing a (bt,kz) B'-slab
    // differ by 128 -> equal bid mod 8 -> same XCD -> slab L2-shared.
    int ot = bid >> 7;            // 0..3
    int kz = (bid >> 5) & 3;      // 0..3
    int bt = bid & 31;            // 0..31
    int brow0 = bt * TM;
    int ocol0 = ot * TN;
    int k0 = kz * KSLICE;

    int wr = w >> 1;              // 0..3 : M sub-tile (32 rows of 128)
    int wc = w & 1;               // 0..1 : N sub-tile (64 cols of 128)

    f32x4 acc[2][4];
#pragma unroll
    for (int m = 0; m < 2; m++)
#pragma unroll
        for (int n = 0; n < 4; n++) acc[m][n] = (f32x4){0.f, 0.f, 0.f, 0.f};

    // staging: 32 x 1KB issues/step (16 for Xs=B' 128 rows, 16 for Ys=A'
    // 128 rows); wave w owns f = 4w..4w+3. LDS dst linear: f*1024.
    int lr = lane >> 3;           // row within 8-row group
    int lcb = (lane & 7) * 8;     // 16B chunk within 64-col row
    const ushort_t* src[4];
    int ldsoff[4];
#pragma unroll
    for (int i = 0; i < 4; i++) {
        int f = w * 4 + i;
        const ushort_t* basep = (f < 16)
            ? Bt + (size_t)(brow0 + f * 8 + lr) * KDIM
            : A  + (size_t)(ocol0 + (f - 16) * 8 + lr) * KDIM;
        src[i] = basep + k0 + lcb;
        ldsoff[i] = f * 1024;
    }
    char* ringb = (char*)ring;

// stages the NEXT tile (pointers auto-advance); each tile = 4 issues/wave
#define STAGE(B) do { char* bb_ = ringb + (B) * BUF_BYTES;                     \
    _Pragma("unroll") for (int i_ = 0; i_ < 4; i_++) {                         \
        gld16(src[i_], bb_ + ldsoff[i_]); src[i_] += BK; } } while (0)

#define COMPUTE(B) do {                                                        \
    const ushort_t* Xs_ = ring + (B) * BUF_ELEMS;                              \
    const ushort_t* Ys_ = Xs_ + TM * BK;                                       \
    int xrow_ = wr * 32 + (lane & 15);                                         \
    int yrow_ = wc * 64 + (lane & 15);                                         \
    int swz_ = (lane & 7) << 3;                                                \
    _Pragma("unroll") for (int kk_ = 0; kk_ < 2; kk_++) {                      \
        int kofs_ = (kk_ * 32 + ((lane >> 4) << 3)) ^ swz_;                    \
        short8 xf[2], yf[4];                                                   \
        _Pragma("unroll") for (int m_ = 0; m_ < 2; m_++)                       \
            xf[m_] = *(const short8*)&Xs_[(xrow_ + m_ * 16) * BK + kofs_];     \
        _Pragma("unroll") for (int n_ = 0; n_ < 4; n_++)                       \
            yf[n_] = *(const short8*)&Ys_[(yrow_ + n_ * 16) * BK + kofs_];     \
        _Pragma("unroll") for (int m_ = 0; m_ < 2; m_++)                       \
            _Pragma("unroll") for (int n_ = 0; n_ < 4; n_++)                   \
                acc[m_][n_] = __builtin_amdgcn_mfma_f32_16x16x32_bf16(         \
                    xf[m_], yf[n_], acc[m_][n_], 0, 0, 0);                     \
    } } while (0)

#define WAITVM(N) asm volatile("s_waitcnt vmcnt(" #N ")" ::: "memory")
#define BARRIER() do { __builtin_amdgcn_sched_barrier(0);                      \
    __builtin_amdgcn_s_barrier();                                              \
    __builtin_amdgcn_sched_barrier(0); } while (0)

    // prologue: 2 tiles in flight (8 gld16/wave outstanding)
    STAGE(0); STAGE(1);
    // steady: wait tile t (leave 4 = tile t+1 in flight), barrier (tile t
    // now fully in LDS across all waves), compute t, barrier (all waves
    // done reading buf t&1), stage tile t+2 into buf t&1.
    for (int t = 0; t < NT - 2; ++t) {
        WAITVM(4);
        BARRIER();
        COMPUTE(t & 1);
        BARRIER();
        STAGE(t & 1);
    }
    WAITVM(4); BARRIER(); COMPUTE(NT & 1);        // tile NT-2
    WAITVM(0); BARRIER(); COMPUTE((NT - 1) & 1);  // tile NT-1

    // epilogue: C/D layout col=lane&15, row=(lane>>4)*4+reg (m89)
    int rgrp = (lane >> 4) * 4;
    int cidx = lane & 15;
#pragma unroll
    for (int m = 0; m < 2; m++) {
#pragma unroll
        for (int n = 0; n < 4; n++) {
            int o_idx = ocol0 + wc * 64 + n * 16 + cidx;
            int b_base = brow0 + wr * 32 + m * 16 + rgrp;
#pragma unroll
            for (int r = 0; r < 4; r++)
                atomicAdd(out + (size_t)(b_base + r) * OUT_DIM + o_idx, acc[m][n][r]);
        }
    }
#undef STAGE
#undef COMPUTE
#undef WAITVM
#undef BARRIER
}

extern "C" void kernel_launch(void* const* d_in, const int* in_sizes, int n_in,
                              void* d_out, int out_size, void* d_ws, size_t ws_size,
                              hipStream_t stream) {
    const float* x     = (const float*)d_in[0];
    const float* w_b   = (const float*)d_in[1];
    const float* w_s   = (const float*)d_in[2];
    const float* ctrl  = (const float*)d_in[3];
    const float* g     = (const float*)d_in[4];
    const float* bound = (const float*)d_in[5];
    float* out = (float*)d_out;

    ushort_t* Abuf = (ushort_t*)d_ws;                               // 512*4608*2 = 4.72 MB
    ushort_t* Bbuf = (ushort_t*)((char*)d_ws + (size_t)(8u << 20)); // at 8 MB; 4096*4608*2 = 37.75 MB

    prep_AB<<<BATCH + OUT_DIM, 512, 0, stream>>>(x, g, bound, w_b, w_s, ctrl,
                                                 Bbuf, Abuf, out);
    gemm_kan<<<(BATCH / TM) * (OUT_DIM / TN) * SPLITK, 512, 0, stream>>>(Abuf, Bbuf, out);
}

// Round 7
// 55.823 us; speedup vs baseline: 1.3218x; 1.2100x over previous
//
#include <hip/hip_runtime.h>
#include <hip/hip_bf16.h>

#define IN_DIM 512
#define OUT_DIM 512
#define BATCH 4096
#define NC 9                  // 8 active spline basis slots + 1 silu slot
#define KDIM (IN_DIM * NC)    // 4608
#define NCTRL 17
#define TM 128                // batch rows per block
#define TN 128                // out cols per block
#define BK 64
#define SPLITK 4
#define KSLICE (KDIM / SPLITK)   // 1152
#define NT (KSLICE / BK)         // 18 K-steps per block
// ring-2: 2 x (TM+TN)*BK bf16 = 2 x 32768 B = 64 KiB LDS -> 2 blocks/CU
#define BUF_ELEMS ((TM + TN) * BK)   // 16384
#define BUF_BYTES (BUF_ELEMS * 2)    // 32768
#define OUT_ELEMS ((size_t)BATCH * OUT_DIM)   // 2M

typedef unsigned short ushort_t;
typedef __attribute__((ext_vector_type(8))) short short8;
typedef __attribute__((ext_vector_type(4))) float f32x4;

__device__ inline ushort_t to_bf16(float f) {
    union { float f; unsigned int i; } v; v.f = f;
    unsigned int r = v.i + 0x7FFF + ((v.i >> 16) & 1);   // round-to-nearest-even
    return (ushort_t)(r >> 16);
}

__device__ inline void gld16(const ushort_t* g, void* l) {
    __builtin_amdgcn_global_load_lds(
        (const __attribute__((address_space(1))) void*)g,
        (__attribute__((address_space(3))) void*)l, 16, 0, 0);
}

// Pre-swizzled storage: element (row R, col k) lives at col k ^ ((R&7)<<3).
// XOR permutes 16B chunks inside each 128B segment: linear global_load_lds
// staging of 64-col tiles is unaffected; ds_read applies the same XOR.
// Verified conflict-free (SQ_LDS_BANK_CONFLICT == 0 in R2/R4/R5/R6).

// Fused prep: blocks [0,BATCH) build B' rows, blocks [BATCH,BATCH+OUT_DIM)
// build A' rows. Stage swizzled row in LDS -> coalesced 16B stores.
__global__ __launch_bounds__(512) void prep_AB(const float* __restrict__ x,
                                               const float* __restrict__ g,
                                               const float* __restrict__ bound_p,
                                               const float* __restrict__ w_b,
                                               const float* __restrict__ w_s,
                                               const float* __restrict__ ctrl,
                                               ushort_t* __restrict__ Bt,
                                               ushort_t* __restrict__ A) {
    __shared__ ushort_t rowbuf[KDIM];
    int blk = blockIdx.x;
    int i = threadIdx.x;
    ushort_t* dstrow;
    if (blk < BATCH) {
        int b = blk;
        float bound = bound_p[0];
        float t = x[(size_t)b * IN_DIM + i];
        t = fminf(fmaxf(t, -bound), bound);
        float u = (t + 8.0f) * 0.625f;       // knot spacing 1.6
        int j = (int)u;                       // g[j] <= t < g[j+1], j in [2,7]
        j = min(max(j, 2), 7);
        float gj[6];
#pragma unroll
        for (int r = 0; r < 6; r++) gj[r] = g[j - 2 + r];
        // de Boor; uniform knots -> denominators are p*1.6 (constants)
        const float invph[4] = {0.f, 0.625f, 0.3125f, 0.2083333333f};
        float Nv[4]; Nv[0] = 1.0f;
        float lv[4], rv[4];
#pragma unroll
        for (int p = 1; p <= 3; p++) {
            lv[p] = t - gj[3 - p];
            rv[p] = gj[2 + p] - t;
            float saved = 0.0f;
#pragma unroll
            for (int r = 0; r < p; r++) {
                float temp = Nv[r] * invph[p];
                Nv[r] = saved + rv[r + 1] * temp;
                saved = lv[p - r] * temp;
            }
            Nv[p] = saved;
        }
        int c0 = j - 3;                       // c0==-1 at j==2: Nv[0] (B_{-1}) dropped
        int swz = (b & 7) << 3;
        int k0 = i * NC;
#pragma unroll
        for (int c = 0; c < 8; c++) {
            float v = 0.0f;
            v = (c == c0    ) ? Nv[0] : v;
            v = (c == c0 + 1) ? Nv[1] : v;
            v = (c == c0 + 2) ? Nv[2] : v;
            v = (c == c0 + 3) ? Nv[3] : v;
            rowbuf[(k0 + c) ^ swz] = to_bf16(v);
        }
        float sg = 1.0f / (1.0f + __expf(-t));
        rowbuf[(k0 + 8) ^ swz] = to_bf16(t * sg);
        dstrow = Bt + (size_t)b * KDIM;
    } else {
        int o = blk - BATCH;
        float ws = w_s[(size_t)i * OUT_DIM + o];
        float wb = w_b[(size_t)i * OUT_DIM + o];
        const float* cp = ctrl + ((size_t)i * OUT_DIM + o) * NCTRL;
        int swz = (o & 7) << 3;
        int k0 = i * NC;
#pragma unroll
        for (int c = 0; c < 8; c++) rowbuf[(k0 + c) ^ swz] = to_bf16(ws * cp[c]);
        rowbuf[(k0 + 8) ^ swz] = to_bf16(wb);
        dstrow = A + (size_t)o * KDIM;
    }
    __syncthreads();
    const uint4* s = (const uint4*)rowbuf;               // 576 x 16B chunks
    uint4* d = (uint4*)dstrow;
    d[i] = s[i];
    if (i < 64) d[512 + i] = s[512 + i];
}

// partial[kz][b][o] = sum_{k in slice kz} B'[b][k] * A'[o][k].
// TM=TN=128, 8 waves (4x2 of 32x64, acc 2x4), BK=64, ring-2 LDS (64 KB ->
// 2 blocks/CU -> 4 waves/SIMD), counted vmcnt (never 0 in main loop),
// 2 barriers/step. Plain fp32 stores to per-kz partial (NO atomics).
__global__ __launch_bounds__(512, 4) void gemm_kan(const ushort_t* __restrict__ A,
                                                   const ushort_t* __restrict__ Bt,
                                                   float* __restrict__ partial) {
    __shared__ ushort_t ring[2 * BUF_ELEMS];   // 64 KiB
    int tid = threadIdx.x;
    int lane = tid & 63;
    int w = tid >> 6;             // 0..7
    int bid = blockIdx.x;
    // bid = ot*128 + kz*32 + bt: the 4 ot-blocks sharing a (bt,kz) B'-slab
    // differ by 128 -> equal bid mod 8 -> same XCD -> slab L2-shared.
    int ot = bid >> 7;            // 0..3
    int kz = (bid >> 5) & 3;      // 0..3
    int bt = bid & 31;            // 0..31
    int brow0 = bt * TM;
    int ocol0 = ot * TN;
    int k0 = kz * KSLICE;

    int wr = w >> 1;              // 0..3 : M sub-tile (32 rows of 128)
    int wc = w & 1;               // 0..1 : N sub-tile (64 cols of 128)

    f32x4 acc[2][4];
#pragma unroll
    for (int m = 0; m < 2; m++)
#pragma unroll
        for (int n = 0; n < 4; n++) acc[m][n] = (f32x4){0.f, 0.f, 0.f, 0.f};

    // staging: 32 x 1KB issues/step (16 for Xs=B' 128 rows, 16 for Ys=A'
    // 128 rows); wave w owns f = 4w..4w+3. LDS dst linear: f*1024.
    int lr = lane >> 3;           // row within 8-row group
    int lcb = (lane & 7) * 8;     // 16B chunk within 64-col row
    const ushort_t* src[4];
    int ldsoff[4];
#pragma unroll
    for (int i = 0; i < 4; i++) {
        int f = w * 4 + i;
        const ushort_t* basep = (f < 16)
            ? Bt + (size_t)(brow0 + f * 8 + lr) * KDIM
            : A  + (size_t)(ocol0 + (f - 16) * 8 + lr) * KDIM;
        src[i] = basep + k0 + lcb;
        ldsoff[i] = f * 1024;
    }
    char* ringb = (char*)ring;

// stages the NEXT tile (pointers auto-advance); each tile = 4 issues/wave
#define STAGE(B) do { char* bb_ = ringb + (B) * BUF_BYTES;                     \
    _Pragma("unroll") for (int i_ = 0; i_ < 4; i_++) {                         \
        gld16(src[i_], bb_ + ldsoff[i_]); src[i_] += BK; } } while (0)

#define COMPUTE(B) do {                                                        \
    const ushort_t* Xs_ = ring + (B) * BUF_ELEMS;                              \
    const ushort_t* Ys_ = Xs_ + TM * BK;                                       \
    int xrow_ = wr * 32 + (lane & 15);                                         \
    int yrow_ = wc * 64 + (lane & 15);                                         \
    int swz_ = (lane & 7) << 3;                                                \
    _Pragma("unroll") for (int kk_ = 0; kk_ < 2; kk_++) {                      \
        int kofs_ = (kk_ * 32 + ((lane >> 4) << 3)) ^ swz_;                    \
        short8 xf[2], yf[4];                                                   \
        _Pragma("unroll") for (int m_ = 0; m_ < 2; m_++)                       \
            xf[m_] = *(const short8*)&Xs_[(xrow_ + m_ * 16) * BK + kofs_];     \
        _Pragma("unroll") for (int n_ = 0; n_ < 4; n_++)                       \
            yf[n_] = *(const short8*)&Ys_[(yrow_ + n_ * 16) * BK + kofs_];     \
        _Pragma("unroll") for (int m_ = 0; m_ < 2; m_++)                       \
            _Pragma("unroll") for (int n_ = 0; n_ < 4; n_++)                   \
                acc[m_][n_] = __builtin_amdgcn_mfma_f32_16x16x32_bf16(         \
                    xf[m_], yf[n_], acc[m_][n_], 0, 0, 0);                     \
    } } while (0)

#define WAITVM(N) asm volatile("s_waitcnt vmcnt(" #N ")" ::: "memory")
#define BARRIER() do { __builtin_amdgcn_sched_barrier(0);                      \
    __builtin_amdgcn_s_barrier();                                              \
    __builtin_amdgcn_sched_barrier(0); } while (0)

    // prologue: 2 tiles in flight (8 gld16/wave outstanding)
    STAGE(0); STAGE(1);
    // steady: wait tile t (leave 4 = tile t+1 in flight), barrier (tile t
    // now fully in LDS across all waves), compute t, barrier (all waves
    // done reading buf t&1), stage tile t+2 into buf t&1.
    for (int t = 0; t < NT - 2; ++t) {
        WAITVM(4);
        BARRIER();
        COMPUTE(t & 1);
        BARRIER();
        STAGE(t & 1);
    }
    WAITVM(4); BARRIER(); COMPUTE(NT & 1);        // tile NT-2
    WAITVM(0); BARRIER(); COMPUTE((NT - 1) & 1);  // tile NT-1

    // epilogue: plain fp32 stores to this kz's partial buffer.
    // C/D layout col=lane&15, row=(lane>>4)*4+reg (m89)
    float* pout = partial + (size_t)kz * OUT_ELEMS;
    int rgrp = (lane >> 4) * 4;
    int cidx = lane & 15;
#pragma unroll
    for (int m = 0; m < 2; m++) {
#pragma unroll
        for (int n = 0; n < 4; n++) {
            int o_idx = ocol0 + wc * 64 + n * 16 + cidx;
            int b_base = brow0 + wr * 32 + m * 16 + rgrp;
#pragma unroll
            for (int r = 0; r < 4; r++)
                pout[(size_t)(b_base + r) * OUT_DIM + o_idx] = acc[m][n][r];
        }
    }
#undef STAGE
#undef COMPUTE
#undef WAITVM
#undef BARRIER
}

// out = p0 + p1 + p2 + p3, fully coalesced f32x4.
__global__ __launch_bounds__(256) void reduce_k(const float* __restrict__ p,
                                                float* __restrict__ out) {
    size_t idx = (size_t)blockIdx.x * 256 + threadIdx.x;   // f32x4 index
    const size_t N4 = OUT_ELEMS / 4;
    const f32x4* pv = (const f32x4*)p;
    f32x4 a = pv[idx];
    f32x4 b = pv[idx + N4];
    f32x4 c = pv[idx + 2 * N4];
    f32x4 d = pv[idx + 3 * N4];
    ((f32x4*)out)[idx] = (a + b) + (c + d);
}

extern "C" void kernel_launch(void* const* d_in, const int* in_sizes, int n_in,
                              void* d_out, int out_size, void* d_ws, size_t ws_size,
                              hipStream_t stream) {
    const float* x     = (const float*)d_in[0];
    const float* w_b   = (const float*)d_in[1];
    const float* w_s   = (const float*)d_in[2];
    const float* ctrl  = (const float*)d_in[3];
    const float* g     = (const float*)d_in[4];
    const float* bound = (const float*)d_in[5];
    float* out = (float*)d_out;

    ushort_t* Abuf = (ushort_t*)d_ws;                               // 512*4608*2  = 4.72 MB @ 0
    ushort_t* Bbuf = (ushort_t*)((char*)d_ws + (size_t)(8u << 20)); // 4096*4608*2 = 37.75 MB @ 8 MB
    float* partial = (float*)((char*)d_ws + (size_t)(48u << 20));   // 4*2M*4 = 33.55 MB @ 48 MB

    prep_AB<<<BATCH + OUT_DIM, 512, 0, stream>>>(x, g, bound, w_b, w_s, ctrl,
                                                 Bbuf, Abuf);
    gemm_kan<<<(BATCH / TM) * (OUT_DIM / TN) * SPLITK, 512, 0, stream>>>(Abuf, Bbuf, partial);
    reduce_k<<<OUT_ELEMS / 4 / 256, 256, 0, stream>>>(partial, out);
}